// Round 10
// baseline (296.194 us; speedup 1.0000x reference)
//
#include <hip/hip_runtime.h>
#include <hip/hip_bf16.h>
#include <math.h>

#define NN 8192      // nodes
#define NK 64        // clusters
#define EPSF 1e-6f
#define NWIN 128     // col-windows of 64
// pass_e: block = 256 rows x 64-col window; grid = 128 windows x 32 bands = 4096.
// Wave w owns 64 rows (4 sub-bands of 16); B-frags register-resident (loaded once);
// wave-private single-buffer LDS tile; zero barriers in main loop; zero global
// loads in MFMA phase.

typedef __attribute__((ext_vector_type(8))) short s16x8;
typedef __attribute__((ext_vector_type(4))) short s16x4;
typedef __attribute__((ext_vector_type(4))) float f32x4;

static __device__ __forceinline__ short f2bf(float x) {
    union { float f; unsigned u; } v; v.f = x;
    unsigned r = (v.u + 0x7fffu + ((v.u >> 16) & 1u)) >> 16;
    return (short)r;
}

// ---------- pre-kernel: A -> ATF fragment-major bf16, + fused argmax/counts/sums ----------
// ATF[((chunk*4 + nf)*64 + l)*8 + e] = bf16(A[chunk*32 + 8*(l>>4) + e][16*nf + (l&15)])
__global__ __launch_bounds__(256) void cvt_at(const float* __restrict__ A,
                                              const float* __restrict__ pos,
                                              unsigned short* __restrict__ ATF,
                                              int* __restrict__ ids,
                                              float* __restrict__ counts,
                                              float* __restrict__ sums) {
    __shared__ unsigned short T[64][72];   // [k][node-local]
    int tid = threadIdx.x;
    int n0 = blockIdx.x * 64;
    int node = tid >> 2;
    int g = tid & 3;
    int k4 = g << 4;
    const float* ap = A + (size_t)(n0 + node) * NK + k4;
    f32x4 x0 = *(const f32x4*)(ap);
    f32x4 x1 = *(const f32x4*)(ap + 4);
    f32x4 x2 = *(const f32x4*)(ap + 8);
    f32x4 x3 = *(const f32x4*)(ap + 12);
#pragma unroll
    for (int e = 0; e < 4; ++e) {
        T[k4 + e][node]      = (unsigned short)f2bf(x0[e]);
        T[k4 + 4 + e][node]  = (unsigned short)f2bf(x1[e]);
        T[k4 + 8 + e][node]  = (unsigned short)f2bf(x2[e]);
        T[k4 + 12 + e][node] = (unsigned short)f2bf(x3[e]);
    }
    // fused argmax over this node's 64 assignments (first-max semantics)
    {
        float mv = x0[0]; int mi = k4;
#pragma unroll
        for (int e = 0; e < 4; ++e) {
            if (x0[e] > mv) { mv = x0[e]; mi = k4 + e; }
            if (x1[e] > mv) { mv = x1[e]; mi = k4 + 4 + e; }
            if (x2[e] > mv) { mv = x2[e]; mi = k4 + 8 + e; }
            if (x3[e] > mv) { mv = x3[e]; mi = k4 + 12 + e; }
        }
#pragma unroll
        for (int m = 1; m < 4; m <<= 1) {
            float ov = __shfl_xor(mv, m);
            int oi = __shfl_xor(mi, m);
            if (ov > mv || (ov == mv && oi < mi)) { mv = ov; mi = oi; }
        }
        if (g == 0) {
            ids[n0 + node] = mi;
            atomicAdd(&counts[mi], 1.0f);
            atomicAdd(&sums[mi * 2 + 0], pos[(size_t)(n0 + node) * 2 + 0]);
            atomicAdd(&sums[mi * 2 + 1], pos[(size_t)(n0 + node) * 2 + 1]);
        }
    }
    __syncthreads();
#pragma unroll
    for (int pass = 0; pass < 2; ++pass) {
        int oi = pass * 256 + tid;              // 512 outputs x 16B
        int l = oi & 63, nf = (oi >> 6) & 3, cl = oi >> 8;
        int k = (l & 15) + 16 * nf;
        int nb = cl * 32 + (l >> 4) * 8;
        s16x8 v;
#pragma unroll
        for (int e = 0; e < 8; ++e) v[e] = (short)T[k][nb + e];
        size_t chunk = (size_t)blockIdx.x * 2 + cl;
        *(s16x8*)(ATF + ((chunk * 4 + nf) * 64 + l) * 8) = v;
    }
}

// ---------- main pass ----------
__global__ __launch_bounds__(256, 4) void pass_e(
    const float* __restrict__ E, const float* __restrict__ A,
    const unsigned short* __restrict__ ATF,
    float* __restrict__ rowsum_part, float* __restrict__ colsum,
    float* __restrict__ within_part)
{
    __shared__ unsigned short Ebf[4][2048];   // per-wave 4KB: [16 rows][64 cols] swizzled
    __shared__ float csum[4][64];
    __shared__ float red[4];

    int tid = threadIdx.x;
    int w = tid >> 6, l = tid & 63;
    int bid = blockIdx.x;
    int window = bid >> 5;        // 0..127
    int band = bid & 31;          // 0..31
    int jbase = window * 64;
    int row0 = band * 256 + w * 64;
    int lm = l & 15, lg = l >> 4;

    // ---- B-fragments: register-resident, loaded ONCE (2 chunks x 4 nf) ----
    s16x8 bf[2][4];
    {
        const unsigned short* ab = ATF + (size_t)(window * 2) * 2048 + (size_t)l * 8;
#pragma unroll
        for (int c = 0; c < 2; ++c)
#pragma unroll
            for (int nf = 0; nf < 4; ++nf)
                bf[c][nf] = *(const s16x8*)(ab + c * 2048 + nf * 512);
    }

    s16x8 ONES;
#pragma unroll
    for (int e = 0; e < 8; ++e) ONES[e] = (short)0x3F80;  // bf16 1.0

    f32x4 csr = {0.f, 0.f, 0.f, 0.f};
    float wsum = 0.f;

    char* buf = (char*)&Ebf[w][0];
    const float* ebase = E + (size_t)row0 * NN + jbase + 4 * lm;
    unsigned wbase = 8u * (unsigned)lm;       // byte col offset in 128B row

    f32x4 ld[4];
#pragma unroll
    for (int q = 0; q < 4; ++q)
        ld[q] = *(const f32x4*)(ebase + (size_t)(4 * q + lg) * NN);

#pragma unroll
    for (int s = 0; s < 4; ++s) {
        // ---- stage sub-band s: colsum accum, cvt, wave-private swizzled ds_write ----
#pragma unroll
        for (int q = 0; q < 4; ++q) {
            f32x4 v = ld[q];
            csr[0] += v[0]; csr[1] += v[1]; csr[2] += v[2]; csr[3] += v[3];
            s16x4 b; b[0] = f2bf(v[0]); b[1] = f2bf(v[1]); b[2] = f2bf(v[2]); b[3] = f2bf(v[3]);
            int row = 4 * q + lg;
            *(s16x4*)(buf + row * 128 + (wbase ^ ((unsigned)(row & 7) << 4))) = b;
        }
        // ---- prefetch next sub-band's E (stays in flight through MFMA) ----
        if (s < 3) {
            const float* pn = ebase + (size_t)(16 * (s + 1)) * NN;
#pragma unroll
            for (int q = 0; q < 4; ++q)
                ld[q] = *(const f32x4*)(pn + (size_t)(4 * q + lg) * NN);
        }
        // ---- MFMA: 2 chunks x (4 within + 1 rowsum); zero global loads ----
        f32x4 D0 = {0.f,0.f,0.f,0.f}, D1 = D0, D2 = D0, D3 = D0, Dr = D0;
#pragma unroll
        for (int c = 0; c < 2; ++c) {
            s16x8 af = *(const s16x8*)(buf + lm * 128 +
                        (((unsigned)(c * 64 + lg * 16)) ^ ((unsigned)(lm & 7) << 4)));
            D0 = __builtin_amdgcn_mfma_f32_16x16x32_bf16(af, bf[c][0], D0, 0, 0, 0);
            D1 = __builtin_amdgcn_mfma_f32_16x16x32_bf16(af, bf[c][1], D1, 0, 0, 0);
            D2 = __builtin_amdgcn_mfma_f32_16x16x32_bf16(af, bf[c][2], D2, 0, 0, 0);
            D3 = __builtin_amdgcn_mfma_f32_16x16x32_bf16(af, bf[c][3], D3, 0, 0, 0);
            Dr = __builtin_amdgcn_mfma_f32_16x16x32_bf16(af, ONES, Dr, 0, 0, 0);
        }
        // ---- dump: rowsum plain store + within dot ----
        int rbase = row0 + 16 * s;
        if (lm == 0)
            *(f32x4*)&rowsum_part[(size_t)window * NN + rbase + 4 * lg] = Dr;
        const float* Ab = A + (size_t)(rbase + 4 * lg) * NK + lm;
#pragma unroll
        for (int r = 0; r < 4; ++r) {
            const float* ar = Ab + (size_t)r * NK;
            wsum += D0[r] * ar[0] + D1[r] * ar[16] + D2[r] * ar[32] + D3[r] * ar[48];
        }
    }

    // ---- epilogue: colsum combine (lanes l, l^16, l^32, l^48 share cols) ----
#pragma unroll
    for (int j = 0; j < 4; ++j) {
        csr[j] += __shfl_xor(csr[j], 16);
        csr[j] += __shfl_xor(csr[j], 32);
    }
    if (l < 16) *(f32x4*)&csum[w][4 * l] = csr;
#pragma unroll
    for (int m = 1; m < 64; m <<= 1) wsum += __shfl_xor(wsum, m);
    if (l == 0) red[w] = wsum;
    __syncthreads();
    if (tid < 64) {
        float sv = (csum[0][tid] + csum[1][tid]) + (csum[2][tid] + csum[3][tid]);
        atomicAdd(&colsum[jbase + tid], sv);
    }
    if (tid == 0) within_part[bid] = red[0] + red[1] + red[2] + red[3];
}

// ---------- reduce rowsum partials (no atomics anywhere) ----------
__global__ __launch_bounds__(256) void reduce_rows(const float* __restrict__ part,
                                                   float* __restrict__ rowsum) {
    int i = blockIdx.x * 256 + threadIdx.x;
    float s = 0.f;
    for (int wdw = 0; wdw < NWIN; ++wdw) s += part[(size_t)wdw * NN + i];
    rowsum[i] = s;
}

// ---------- spatial pass 2: distances to centroids ----------
__global__ __launch_bounds__(256) void spatial2(
    const int* __restrict__ ids, const float* __restrict__ pos,
    const float* __restrict__ counts, const float* __restrict__ sums,
    float* __restrict__ distsum, int* __restrict__ maxid)
{
    __shared__ float ds[64];
    __shared__ int mx;
    int tid = threadIdx.x;
    if (tid < 64) ds[tid] = 0.f;
    if (tid == 0) mx = 0;
    __syncthreads();
    int i = blockIdx.x * 256 + tid;
    int id = ids[i];
    float den = counts[id] + EPSF;
    float cx = sums[id * 2 + 0] / den;
    float cy = sums[id * 2 + 1] / den;
    float dx = pos[(size_t)i * 2 + 0] - cx;
    float dy = pos[(size_t)i * 2 + 1] - cy;
    atomicAdd(&ds[id], sqrtf(dx * dx + dy * dy));
    atomicMax(&mx, id);
    __syncthreads();
    if (tid < 64) atomicAdd(&distsum[tid], ds[tid]);
    if (tid == 0) atomicMax(maxid, mx);
}

// ---------- finalize ----------
__global__ __launch_bounds__(256) void finalize(
    const float* __restrict__ rowsum, const float* __restrict__ colsum,
    const float* __restrict__ cons, const float* __restrict__ gen,
    const float* __restrict__ within_part, const float* __restrict__ counts,
    const float* __restrict__ distsum, const int* __restrict__ maxid,
    float* __restrict__ out)
{
    __shared__ float redb[4], rede[4], redw[4];
    int tid = threadIdx.x;
    int w = tid >> 6, l = tid & 63;
    float bacc = 0.f, eacc = 0.f, wacc = 0.f;
    for (int i = tid; i < NN; i += 256) {
        float imb = (cons[i] - gen[i]) - (colsum[i] - rowsum[i]);
        bacc += imb * imb;
        eacc += rowsum[i];
    }
    for (int i = tid; i < 4096; i += 256) wacc += within_part[i];
#pragma unroll
    for (int m = 1; m < 64; m <<= 1) {
        bacc += __shfl_xor(bacc, m);
        eacc += __shfl_xor(eacc, m);
        wacc += __shfl_xor(wacc, m);
    }
    if (l == 0) { redb[w] = bacc; rede[w] = eacc; redw[w] = wacc; }
    __syncthreads();

    float sacc = 0.f;
    if (tid < 64) {
        float c = counts[tid];
        float avg = distsum[tid] / (c + EPSF);
        sacc = (c >= 2.0f) ? avg : 0.f;
#pragma unroll
        for (int m = 1; m < 64; m <<= 1) sacc += __shfl_xor(sacc, m);
    }
    if (tid == 0) {
        float balance = (redb[0] + redb[1] + redb[2] + redb[3]) / (float)NN;
        float sumE = rede[0] + rede[1] + rede[2] + rede[3];
        float W = redw[0] + redw[1] + redw[2] + redw[3];
        float clustering = (sumE - 2.0f * W) / ((float)NN * (float)NN + EPSF);
        float nc = (float)(maxid[0] + 1) + EPSF;
        float spatial = sacc / nc;
        float total = 1.0f * balance + 0.5f * spatial + 0.3f * clustering;
        out[0] = total;
        out[1] = balance;
        out[2] = spatial;
        out[3] = clustering;
    }
}

extern "C" void kernel_launch(void* const* d_in, const int* in_sizes, int n_in,
                              void* d_out, int out_size, void* d_ws, size_t ws_size,
                              hipStream_t stream) {
    const float* E    = (const float*)d_in[0];
    const float* A    = (const float*)d_in[1];
    const float* pos  = (const float*)d_in[2];
    const float* cons = (const float*)d_in[3];
    const float* gen  = (const float*)d_in[4];
    float* out = (float*)d_out;

    char* ws = (char*)d_ws;
    unsigned short* ATF = (unsigned short*)ws;                 // 1 MB fragment-major
    float* rowsum_part = (float*)(ws + (size_t)2 * NK * NN);   // [128][N] = 4 MB
    float* rowsum      = rowsum_part + (size_t)NWIN * NN;      // [N]
    float* colsum      = rowsum + NN;                          // [N]    <- zero from here
    float* counts      = colsum + NN;                          // [64]
    float* sums        = counts + 64;                          // [64][2]
    float* distsum     = sums + 128;                           // [64]
    int*   maxid       = (int*)(distsum + 64);                 // [1]    <- zero to here
    float* within_part = (float*)(maxid + 1);                  // [4096]
    int*   ids         = (int*)(within_part + 4096);           // [N]

    size_t zbytes = ((size_t)NN + 64 + 128 + 64 + 1) * 4;
    hipMemsetAsync(colsum, 0, zbytes, stream);

    cvt_at     <<<NN / 64, 256, 0, stream>>>(A, pos, ATF, ids, counts, sums);
    pass_e     <<<NWIN * 32, 256, 0, stream>>>(E, A, ATF, rowsum_part, colsum, within_part);
    reduce_rows<<<NN / 256, 256, 0, stream>>>(rowsum_part, rowsum);
    spatial2   <<<NN / 256, 256, 0, stream>>>(ids, pos, counts, sums, distsum, maxid);
    finalize   <<<1, 256, 0, stream>>>(rowsum, colsum, cons, gen, within_part, counts, distsum, maxid, out);
}